// Round 9
// baseline (20.925 us; speedup 1.0000x reference)
//
#include <hip/hip_runtime.h>
#include <math.h>

// query [4,32,64,64] f32, key [4,32,64,192] f32
#define B 4
#define C 32
#define H 64
#define WQ 64
#define WK 192
#define NP 129                    // P = 192 - 64 + 1
#define ROWS (C * H)              // 2048 rows per batch
#define ELEMS (ROWS * WQ)         // 131072 elements per (b,p)
#define GB 64                     // blocks per batch
#define WPB 16                    // waves per block
#define RPW 2                     // rows per wave
#define KPAD 200                  // padded LDS k-row stride

// Kernel A: 256 blocks x 1024 threads (16 waves). Wave = 2 rows; lane l owns
// shifts p=2l, p=2l+1. Rows processed sequentially so each row's 64 q-values
// sit in SGPRs (s_load up-front, no SMEM in the loop). Inner loop is pure
// {ds_read_b64 + VALU} with 4 independent accumulator chains (R8-identical).
// Partials written TRANSPOSED part[(b*NP+p)*GB+g] for coalesced B reads.
__global__ __launch_bounds__(1024, 4) void patch_l1_partial(const float* __restrict__ query,
                                                            const float* __restrict__ key,
                                                            float* __restrict__ part) {
    __shared__ __align__(16) float kbuf[WPB][RPW][KPAD];  // 25.6 KB
    __shared__ float red[WPB][130];                       // 8.3 KB

    const int bid  = blockIdx.x;
    const int b    = bid >> 6;           // / GB
    const int g    = bid & (GB - 1);
    const int t    = threadIdx.x;
    const int wv   = t >> 6;             // 0..15
    const int lane = t & 63;
    const int slot = __builtin_amdgcn_readfirstlane(g * WPB + (t >> 6));
    const int r0   = slot * RPW;         // this wave's two rows

    const float* __restrict__ qb = query + (size_t)b * ELEMS;
    const float* __restrict__ kb = key   + (size_t)b * ROWS * WK + (size_t)r0 * WK;

    // stage both k-rows into wave-private LDS (lane<48: one float4 per row)
    if (lane < 48) {
        const float4 v0 = *reinterpret_cast<const float4*>(kb + lane * 4);
        const float4 v1 = *reinterpret_cast<const float4*>(kb + WK + lane * 4);
        *reinterpret_cast<float4*>(&kbuf[wv][0][lane * 4]) = v0;
        *reinterpret_cast<float4*>(&kbuf[wv][1][lane * 4]) = v1;
    }
    // per-lane q values for the p=128 terms
    const float q0l = qb[(size_t)r0 * WQ + lane];
    const float q1l = qb[(size_t)(r0 + 1) * WQ + lane];

    float acc_a = 0.f, acc_b = 0.f, acc2 = 0.f;

    #pragma unroll
    for (int rr = 0; rr < RPW; ++rr) {
        // hoist the row's q into SGPRs: uniform pointer + compile-time offsets
        const float* __restrict__ qr = qb + (size_t)(r0 + rr) * WQ;
        float qs[64];
        #pragma unroll
        for (int s4 = 0; s4 < 16; ++s4) {
            const float4 qv = *reinterpret_cast<const float4*>(qr + s4 * 4);
            qs[s4 * 4 + 0] = qv.x; qs[s4 * 4 + 1] = qv.y;
            qs[s4 * 4 + 2] = qv.z; qs[s4 * 4 + 3] = qv.w;
        }

        const float* __restrict__ k0 = &kbuf[wv][rr][0];
        float aa0 = 0.f, aa1 = 0.f, bb0 = 0.f, bb1 = 0.f;

        #pragma unroll
        for (int si = 0; si < 16; ++si) {
            const int s = si * 4;
            const float2 ka = *reinterpret_cast<const float2*>(&k0[2 * lane + s]);
            const float2 kc = *reinterpret_cast<const float2*>(&k0[2 * lane + s + 2]);
            aa0 += fabsf(ka.x - qs[s]);                    // p=2l,   w=s
            if (si > 0) bb0 += fabsf(ka.x - qs[s - 1]);    // p=2l+1, w=s-1
            aa1 += fabsf(ka.y - qs[s + 1]);                // p=2l,   w=s+1
            bb1 += fabsf(ka.y - qs[s]);                    // p=2l+1, w=s
            aa0 += fabsf(kc.x - qs[s + 2]);                // p=2l,   w=s+2
            bb0 += fabsf(kc.x - qs[s + 1]);                // p=2l+1, w=s+1
            aa1 += fabsf(kc.y - qs[s + 3]);                // p=2l,   w=s+3
            bb1 += fabsf(kc.y - qs[s + 2]);                // p=2l+1, w=s+2
        }
        bb0 += fabsf(k0[2 * lane + 64] - qs[63]);          // tail: p=2l+1, w=63

        acc_a += aa0 + aa1;
        acc_b += bb0 + bb1;
        acc2  += fabsf(k0[128 + lane] - (rr ? q1l : q0l)); // p=128, w=lane
    }

    // wave-reduce the p=128 accumulator across 64 lanes
    #pragma unroll
    for (int m = 32; m; m >>= 1) acc2 += __shfl_xor(acc2, m, 64);

    *reinterpret_cast<float2*>(&red[wv][2 * lane]) = make_float2(acc_a, acc_b);
    if (lane == 0) red[wv][128] = acc2;
    __syncthreads();

    if (t < NP) {
        float s = 0.f;
        #pragma unroll
        for (int w = 0; w < WPB; ++w) s += red[w][t];
        part[((size_t)b * NP + t) * GB + g] = s;   // transposed: coalesced in B
    }
}

// Kernel B: 4 blocks x 512 threads. Wave wv handles p = wv, wv+8, ...; per p:
// one contiguous 64-lane load + butterfly sum. Register min/argmin (increasing
// p + strict < keeps first index), 8-way cross-wave combine in LDS.
__global__ __launch_bounds__(512) void patch_l1_final(const float* __restrict__ part,
                                                      float* __restrict__ out) {
    const int b    = blockIdx.x;
    const int t    = threadIdx.x;
    const int wv   = t >> 6;       // 0..7
    const int lane = t & 63;

    float best  = INFINITY;
    int   besti = NP;

    for (int p = wv; p < NP; p += 8) {
        float v = part[((size_t)b * NP + p) * GB + lane];
        #pragma unroll
        for (int m = 32; m; m >>= 1) v += __shfl_xor(v, m, 64);
        const float y = v * (1.0f / (float)ELEMS);
        if (y < best) { best = y; besti = p; }
    }

    __shared__ float sy[8];
    __shared__ int   si[8];
    if (lane == 0) { sy[wv] = best; si[wv] = besti; }
    __syncthreads();

    if (t == 0) {
        float yb = sy[0];
        int   ib = si[0];
        #pragma unroll
        for (int w = 1; w < 8; ++w) {
            const float yo = sy[w];
            const int   io = si[w];
            if (yo < yb || (yo == yb && io < ib)) { yb = yo; ib = io; }
        }
        out[b]     = (float)ib;
        out[5 + b] = yb;
        if (b == 0) out[4] = (float)NP;
    }
}

extern "C" void kernel_launch(void* const* d_in, const int* in_sizes, int n_in,
                              void* d_out, int out_size, void* d_ws, size_t ws_size,
                              hipStream_t stream) {
    const float* query = (const float*)d_in[0];
    const float* key   = (const float*)d_in[1];
    float* out  = (float*)d_out;
    float* part = (float*)d_ws;   // B*NP*GB floats = 132 KB, block-owned

    patch_l1_partial<<<B * GB, 1024, 0, stream>>>(query, key, part);
    patch_l1_final<<<B, 512, 0, stream>>>(part, out);
}